// Round 4
// baseline (209.114 us; speedup 1.0000x reference)
//
#include <hip/hip_runtime.h>
#include <hip/hip_bf16.h>

typedef unsigned short u16;
typedef float  f32x4  __attribute__((ext_vector_type(4)));
typedef short  bf16x8 __attribute__((ext_vector_type(8)));
typedef u16    u16x8  __attribute__((ext_vector_type(8)));

#define CDIM 1024
#define HW   16384

typedef const void __attribute__((address_space(1))) gvoid;
typedef void __attribute__((address_space(3))) svoid;

__device__ __forceinline__ u16 f2bf(float f) {
    unsigned u = __float_as_uint(f);
    u += 0x7fffu + ((u >> 16) & 1u);            // RNE
    return (u16)(u >> 16);
}
__device__ __forceinline__ float bf2f(u16 h) { return __uint_as_float(((unsigned)h) << 16); }

__device__ __forceinline__ f32x4 mfma16(bf16x8 a, bf16x8 b, f32x4 c) {
    return __builtin_amdgcn_mfma_f32_16x16x32_bf16(a, b, c, 0, 0, 0);
}

// ---------------- K1: x(f32) -> hi, lo (split bf16) + hiT (fused transpose) ----------------
__global__ __launch_bounds__(256) void k_convert(const float* __restrict__ x,
                                                 u16* __restrict__ hi, u16* __restrict__ lo,
                                                 u16* __restrict__ hiT)
{
    __shared__ u16 tile[64][72];
    const int pb = blockIdx.x;   // HW tile (0..255)
    const int cb = blockIdx.y;   // C tile  (0..15)
    const int tid = threadIdx.x;
#pragma unroll
    for (int pass = 0; pass < 4; ++pass) {
        const int i  = (tid >> 4) + (pass << 4);    // c-row in tile 0..63
        const int j4 = (tid & 15) << 2;             // p-col in tile
        const long gidx = (long)(cb * 64 + i) * HW + pb * 64 + j4;
        const float4 v = *(const float4*)(x + gidx);
        ushort4 h, l;
        h.x = f2bf(v.x); l.x = f2bf(v.x - bf2f(h.x));
        h.y = f2bf(v.y); l.y = f2bf(v.y - bf2f(h.y));
        h.z = f2bf(v.z); l.z = f2bf(v.z - bf2f(h.z));
        h.w = f2bf(v.w); l.w = f2bf(v.w - bf2f(h.w));
        *(ushort4*)(hi + gidx) = h;
        *(ushort4*)(lo + gidx) = l;
        tile[i][j4 + 0] = h.x; tile[i][j4 + 1] = h.y;
        tile[i][j4 + 2] = h.z; tile[i][j4 + 3] = h.w;
    }
    __syncthreads();
#pragma unroll
    for (int pass = 0; pass < 2; ++pass) {
        const int j  = (tid >> 3) + (pass << 5);    // p-row 0..63
        const int c8 = (tid & 7) << 3;
        u16x8 v;
#pragma unroll
        for (int q = 0; q < 8; ++q) v[q] = tile[c8 + q][j];
        *(u16x8*)(hiT + (long)(pb * 64 + j) * CDIM + cb * 64 + c8) = v;
    }
}

// ============ 256x256 8-phase GEMM — faithful m201-template port ============
// A row-major (M x K), B row-major (N x K) -> C[M][N] = A.B^T
// 8 waves = 2M x 4N, per-wave output 128x64, mfma_f32_16x16x32_bf16.
// EPI 0: write split-K partial to C + ks*csplit.   EPI 1: C = gamma*acc + X.

// LDS placement (involution, conflict-light): granule (row, s) of a 128x64 half-tile at
// u16 offset (row>>3)*512 + s*64 + ((row&7)^s)*8.  Staged linearly by global_load_lds
// with the inverse permutation applied to the global source address.
__device__ __forceinline__ void stage_half(const u16* __restrict__ gbase, long ldg,
                                           int rowhalf, int ktile, u16* seg, int tid)
{
    const int lane = tid & 63;
    const int wv   = tid >> 6;
    const int s    = lane >> 3;                 // k-slot 0..7 (16B granules)
    const int r7   = (lane & 7) ^ s;            // row within 8-row region
    const int col  = s << 3;                    // element col of the granule
#pragma unroll
    for (int q = 0; q < 2; ++q) {
        const int j = wv + (q << 3);            // region 0..15
        const u16* src = gbase + (long)((rowhalf << 7) + (j << 3) + r7) * ldg
                               + (ktile << 6) + col;
        __builtin_amdgcn_global_load_lds((gvoid*)src, (svoid*)(seg + (j << 9)), 16, 0, 0);
    }
}

__device__ __forceinline__ bf16x8 rd_frag(const u16* seg, int row, int s)
{
    const int off = ((row >> 3) << 9) + (s << 6) + (((row & 7) ^ s) << 3);
    return *(const bf16x8*)(seg + off);
}

#define RD_A(BUF, QM)                                                          \
    _Pragma("unroll") for (int mf = 0; mf < 4; ++mf)                           \
    _Pragma("unroll") for (int k2 = 0; k2 < 2; ++k2)                           \
        Af[mf][k2] = rd_frag(sA[BUF][wm], (QM) * 64 + mf * 16 + l15, k2 * 4 + lk);

#define RD_B(BUF, QN)                                                          \
    _Pragma("unroll") for (int nf = 0; nf < 2; ++nf)                           \
    _Pragma("unroll") for (int k2 = 0; k2 < 2; ++k2)                           \
        Bf[nf][k2] = rd_frag(sB[BUF][bhalf], bcolbase + (QN) * 32 + nf * 16 + l15, k2 * 4 + lk);

#define MID_BAR()                                                              \
    __builtin_amdgcn_sched_barrier(0);                                         \
    __builtin_amdgcn_s_barrier();                                              \
    asm volatile("s_waitcnt lgkmcnt(0)" ::: "memory");                         \
    __builtin_amdgcn_sched_barrier(0)

#define DO_MFMA(QM, QN)                                                        \
    __builtin_amdgcn_s_setprio(1);                                             \
    _Pragma("unroll") for (int k2 = 0; k2 < 2; ++k2)                           \
    _Pragma("unroll") for (int mf = 0; mf < 4; ++mf)                           \
    _Pragma("unroll") for (int nf = 0; nf < 2; ++nf)                           \
        acc[QM][QN][mf][nf] = mfma16(Af[mf][k2], Bf[nf][k2], acc[QM][QN][mf][nf]); \
    __builtin_amdgcn_s_setprio(0)

#define END_BAR()                                                              \
    __builtin_amdgcn_sched_barrier(0);                                         \
    __builtin_amdgcn_s_barrier();                                              \
    __builtin_amdgcn_sched_barrier(0)

template<int EPI>
__global__ __launch_bounds__(512, 2) void k_gemm8(
    const u16* __restrict__ Amat, const u16* __restrict__ Bhi, const u16* __restrict__ Blo,
    long lda, long ldb, int kchunk, int nbn,
    float* __restrict__ C, long ldc, long csplit,
    const float* __restrict__ X, const float* __restrict__ gamma)
{
    __shared__ u16 sA[2][2][8192];   // [buf][rowhalf][128*64]
    __shared__ u16 sB[2][2][8192];

    const int tid  = threadIdx.x;
    const int lane = tid & 63;
    const int w    = tid >> 6;
    const int wm   = w >> 2;          // 0..1  (row half of 256)
    const int wn   = w & 3;           // 0..3  (64-col strip)
    const int l15  = lane & 15;
    const int lk   = lane >> 4;       // k-group 0..3
    const int bhalf    = wn >> 1;     // B LDS half
    const int bcolbase = (wn & 1) * 64;

    const int ks   = blockIdx.y;
    const int nblk = gridDim.x;
    const int lin  = blockIdx.x;
    const int ti   = (lin & 7) * (nblk >> 3) + (lin >> 3);   // bijective XCD swizzle (nblk%8==0)
    const int bi   = ti / nbn, bn = ti % nbn;

    const u16* Ab = Amat + (long)bi * 256 * lda + (long)ks * kchunk;
    const u16* Bb;
    if (EPI == 0) {
        const int half = nbn >> 1;    // combined B: first half rows from Bhi, second from Blo
        Bb = (bn < half) ? (Bhi + (long)bn * 256 * ldb)
                         : (Blo + (long)(bn - half) * 256 * ldb);
    } else {
        Bb = Bhi + (long)bn * 256 * ldb;
    }
    Bb += (long)ks * kchunk;

    const int nkt = kchunk >> 6;      // even
    const int nit = nkt >> 1;

    f32x4 acc[2][2][4][2];            // [qm][qn][mf][nf]
#pragma unroll
    for (int a = 0; a < 2; ++a)
#pragma unroll
        for (int b = 0; b < 2; ++b)
#pragma unroll
            for (int c = 0; c < 4; ++c)
#pragma unroll
                for (int d = 0; d < 2; ++d) acc[a][b][c][d] = (f32x4){0.f, 0.f, 0.f, 0.f};

    bf16x8 Af[4][2], Bf[2][2];

    // ---- prologue: buf0 all 4 halves + buf1 A-halves; vmcnt(4) keeps buf1-A in flight ----
    stage_half(Ab, lda, 0, 0, sA[0][0], tid);
    stage_half(Ab, lda, 1, 0, sA[0][1], tid);
    stage_half(Bb, ldb, 0, 0, sB[0][0], tid);
    stage_half(Bb, ldb, 1, 0, sB[0][1], tid);
    stage_half(Ab, lda, 0, 1, sA[1][0], tid);
    stage_half(Ab, lda, 1, 1, sA[1][1], tid);
    asm volatile("s_waitcnt vmcnt(4)" ::: "memory");
    __builtin_amdgcn_sched_barrier(0);
    __builtin_amdgcn_s_barrier();
    __builtin_amdgcn_sched_barrier(0);

    for (int it = 0; it < nit; ++it) {
        const int  kt0  = it << 1, kt1 = kt0 + 1;
        const bool lastit = (it == nit - 1);

        // ---- K-tile kt0 from buf0 ----
        // P1: Q(0,0); stage B(kt1)->buf1 (freed at prev P8)
        RD_A(0, 0); RD_B(0, 0);
        stage_half(Bb, ldb, 0, kt1, sB[1][0], tid);
        stage_half(Bb, ldb, 1, kt1, sB[1][1], tid);
        asm volatile("s_waitcnt lgkmcnt(8)" ::: "memory");
        MID_BAR(); DO_MFMA(0, 0); END_BAR();

        // P2: Q(0,1) — A retained
        RD_B(0, 1);
        MID_BAR(); DO_MFMA(0, 1); END_BAR();

        // P3: Q(1,1) — B retained
        RD_A(0, 1);
        MID_BAR(); DO_MFMA(1, 1); END_BAR();

        // P4: Q(1,0) — A retained; stage A(kt0+2)->buf0 (A freed after P3);
        //     vmcnt before trailing barrier => buf1 fully landed for P5 (collective)
        RD_B(0, 0);
        if (!lastit) {
            stage_half(Ab, lda, 0, kt0 + 2, sA[0][0], tid);
            stage_half(Ab, lda, 1, kt0 + 2, sA[0][1], tid);
        }
        MID_BAR(); DO_MFMA(1, 0);
        if (lastit) asm volatile("s_waitcnt vmcnt(0)" ::: "memory");
        else        asm volatile("s_waitcnt vmcnt(4)" ::: "memory");
        END_BAR();

        // ---- K-tile kt1 from buf1 ----
        // P5: Q(0,0); stage B(kt0+2)->buf0 (B freed after P4)
        RD_A(1, 0); RD_B(1, 0);
        if (!lastit) {
            stage_half(Bb, ldb, 0, kt0 + 2, sB[0][0], tid);
            stage_half(Bb, ldb, 1, kt0 + 2, sB[0][1], tid);
        }
        asm volatile("s_waitcnt lgkmcnt(8)" ::: "memory");
        MID_BAR(); DO_MFMA(0, 0); END_BAR();

        // P6: Q(0,1)
        RD_B(1, 1);
        MID_BAR(); DO_MFMA(0, 1); END_BAR();

        // P7: Q(1,1)
        RD_A(1, 1);
        MID_BAR(); DO_MFMA(1, 1); END_BAR();

        // P8: Q(1,0); stage A(kt1+2)->buf1 (A freed after P7); vmcnt(4) => buf0 landed for next P1
        RD_B(1, 0);
        if (!lastit) {
            stage_half(Ab, lda, 0, kt1 + 2, sA[1][0], tid);
            stage_half(Ab, lda, 1, kt1 + 2, sA[1][1], tid);
        }
        MID_BAR(); DO_MFMA(1, 0);
        if (!lastit) asm volatile("s_waitcnt vmcnt(4)" ::: "memory");
        END_BAR();
    }

    // -------- epilogue: C/D layout (m89): col = lane&15, row = (lane>>4)*4 + reg --------
    if (EPI == 0) {
        float* Cb = C + (long)ks * csplit;
#pragma unroll
        for (int qm = 0; qm < 2; ++qm)
#pragma unroll
            for (int qn = 0; qn < 2; ++qn)
#pragma unroll
                for (int mf = 0; mf < 4; ++mf)
#pragma unroll
                    for (int nf = 0; nf < 2; ++nf)
#pragma unroll
                        for (int r = 0; r < 4; ++r) {
                            const int row = bi * 256 + wm * 128 + qm * 64 + mf * 16 + lk * 4 + r;
                            const int col = bn * 256 + wn * 64 + qn * 32 + nf * 16 + l15;
                            Cb[(long)row * ldc + col] = acc[qm][qn][mf][nf][r];
                        }
    } else {
        const float gm = gamma[0];
#pragma unroll
        for (int qm = 0; qm < 2; ++qm)
#pragma unroll
            for (int qn = 0; qn < 2; ++qn)
#pragma unroll
                for (int mf = 0; mf < 4; ++mf)
#pragma unroll
                    for (int nf = 0; nf < 2; ++nf)
#pragma unroll
                        for (int r = 0; r < 4; ++r) {
                            const int row = bi * 256 + wm * 128 + qm * 64 + mf * 16 + lk * 4 + r;
                            const int col = bn * 256 + wn * 64 + qn * 32 + nf * 16 + l15;
                            const long idx = (long)row * ldc + col;
                            C[idx] = gm * acc[qm][qn][mf][nf][r] + X[idx];
                        }
    }
}

// ---------------- K2b: Esym = sum_ks (E1 + E2 + E2^T), E12[ks][1024][2048] ----------------
__global__ __launch_bounds__(256) void k_symmetrize(const float* __restrict__ E12,
                                                    float* __restrict__ Esym)
{
    __shared__ float tr[64][65];
    const int jb = blockIdx.x, ib = blockIdx.y, tid = threadIdx.x;
    float4 accv[4];
#pragma unroll
    for (int e4 = 0; e4 < 4; ++e4) {
        const int e = tid + (e4 << 8);
        const int i = e >> 4, j4 = (e & 15) << 2;
        float ax = 0, ay = 0, az = 0, aw = 0, bx = 0, by = 0, bz = 0, bw = 0;
#pragma unroll
        for (int ks = 0; ks < 8; ++ks) {
            const float* base = E12 + (long)ks * (1024 * 2048);
            float4 p1 = *(const float4*)(base + (long)(ib * 64 + i) * 2048 + jb * 64 + j4);
            float4 p2 = *(const float4*)(base + (long)(ib * 64 + i) * 2048 + 1024 + jb * 64 + j4);
            float4 p3 = *(const float4*)(base + (long)(jb * 64 + i) * 2048 + 1024 + ib * 64 + j4);
            ax += p1.x + p2.x; ay += p1.y + p2.y; az += p1.z + p2.z; aw += p1.w + p2.w;
            bx += p3.x; by += p3.y; bz += p3.z; bw += p3.w;
        }
        accv[e4] = make_float4(ax, ay, az, aw);
        tr[i][j4 + 0] = bx; tr[i][j4 + 1] = by; tr[i][j4 + 2] = bz; tr[i][j4 + 3] = bw;
    }
    __syncthreads();
#pragma unroll
    for (int e4 = 0; e4 < 4; ++e4) {
        const int e = tid + (e4 << 8);
        const int i = e >> 4, j4 = (e & 15) << 2;
        float4 o = accv[e4];
        o.x += tr[j4 + 0][i]; o.y += tr[j4 + 1][i]; o.z += tr[j4 + 2][i]; o.w += tr[j4 + 3][i];
        *(float4*)(Esym + (long)(ib * 64 + i) * CDIM + jb * 64 + j4) = o;
    }
}

// ---------------- K3: att = softmax(-E) rows, stored bf16 ----------------
__global__ __launch_bounds__(256) void k_softmax(const float* __restrict__ E, u16* __restrict__ att)
{
    __shared__ float red[4];
    __shared__ float bcast;
    const int row = blockIdx.x, tid = threadIdx.x;
    const float4 v = ((const float4*)(E + (long)row * CDIM))[tid];

    float m = fminf(fminf(v.x, v.y), fminf(v.z, v.w));
#pragma unroll
    for (int s = 32; s > 0; s >>= 1) m = fminf(m, __shfl_down(m, s));
    if ((tid & 63) == 0) red[tid >> 6] = m;
    __syncthreads();
    if (tid == 0) bcast = fminf(fminf(red[0], red[1]), fminf(red[2], red[3]));
    __syncthreads();
    m = bcast;  // row min of E == row max of -E

    const float px = expf(m - v.x), py = expf(m - v.y), pz = expf(m - v.z), pw = expf(m - v.w);
    float s4 = px + py + pz + pw;
#pragma unroll
    for (int s = 32; s > 0; s >>= 1) s4 += __shfl_down(s4, s);
    if ((tid & 63) == 0) red[tid >> 6] = s4;
    __syncthreads();
    if (tid == 0) bcast = red[0] + red[1] + red[2] + red[3];
    __syncthreads();
    const float inv = 1.0f / bcast;

    ushort4 o;
    o.x = f2bf(px * inv); o.y = f2bf(py * inv); o.z = f2bf(pz * inv); o.w = f2bf(pw * inv);
    ((ushort4*)(att + (long)row * CDIM))[tid] = o;
}

extern "C" void kernel_launch(void* const* d_in, const int* in_sizes, int n_in,
                              void* d_out, int out_size, void* d_ws, size_t ws_size,
                              hipStream_t stream)
{
    (void)in_sizes; (void)n_in; (void)out_size; (void)ws_size;
    const float* x = (const float*)d_in[0];
    const float* gamma = (const float*)d_in[1];
    float* out = (float*)d_out;
    char* ws = (char*)d_ws;

    // Workspace (102 MiB, proven to fit): hi | lo | hiT | Esym | att.
    // Split-K partials (64 MiB) live in d_out, fully overwritten by the final GEMM.
    u16*   hi   = (u16*)ws;                         // 32 MiB
    u16*   lo   = (u16*)(ws + (32ull << 20));       // 32 MiB
    u16*   hiT  = (u16*)(ws + (64ull << 20));       // 32 MiB
    float* Esym = (float*)(ws + (96ull << 20));     //  4 MiB
    u16*   att  = (u16*)(ws + (100ull << 20));      //  2 MiB
    float* E12  = out;                              // 64 MiB scratch (== out buffer)

    k_convert<<<dim3(256, 16), 256, 0, stream>>>(x, hi, lo, hiT);
    // Energy: combined GEMM  M=1024, N=2048 (hi||lo), K=16384, split-K=8.
    k_gemm8<0><<<dim3(32, 8), 512, 0, stream>>>(hi, hi, lo, (long)HW, (long)HW, 2048, 8,
                                                E12, 2048L, 1024L * 2048L, nullptr, nullptr);
    k_symmetrize<<<dim3(16, 16), 256, 0, stream>>>(E12, Esym);
    k_softmax<<<1024, 256, 0, stream>>>(Esym, att);
    // Out: GEMM  M=1024, N=16384, K=1024; epilogue gamma*acc + x.
    k_gemm8<1><<<dim3(256, 1), 512, 0, stream>>>(att, hiT, nullptr, 1024L, 1024L, 1024, 64,
                                                 out, (long)HW, 0L, x, gamma);
}